// Round 5
// baseline (85015.906 us; speedup 1.0000x reference)
//
#include <hip/hip_runtime.h>

namespace {

constexpr int B = 128;
constexpr int T = 1024;
constexpr int DIN = 48;
constexpr int H = 256;
constexpr int G = 4 * H;          // 1024 gate rows per direction
constexpr int NT = 256;           // threads per block

constexpr size_t BH           = (size_t)B * H;                       // 32768
constexpr size_t WT_FLOATS    = 4 * 256 * 1024 + 2 * 48 * 1024 + 2 * 512 * 1024; // 2,195,456
constexpr size_t STATE_FLOATS = 12 * BH;                             // 393,216
constexpr size_t FLAG_INTS    = 8192;                                // 32 grp x 8 members x 16 + barrier
constexpr size_t O0_ELEMS     = (size_t)B * T * 512;                 // 67,108,864

__device__ __forceinline__ float sigmoidf_(float x) {
    float z = __expf(-fabsf(x));
    float s = 1.0f / (1.0f + z);
    return x >= 0.0f ? s : 1.0f - s;
}
__device__ __forceinline__ float tanhf_(float x) {
    float z = __expf(-2.0f * fabsf(x));
    float tp = (1.0f - z) / (1.0f + z);
    return x >= 0.0f ? tp : -tp;
}
__device__ __forceinline__ float bf2f(unsigned short s) {
    union { unsigned int u; float f; } v; v.u = ((unsigned int)s) << 16; return v.f;
}
__device__ __forceinline__ unsigned short f2bf(float f) {
    union { float f; unsigned int u; } v; v.f = f;
    unsigned int u = v.u;
    return (unsigned short)((u + 0x7FFFu + ((u >> 16) & 1u)) >> 16);  // RNE
}
__device__ __forceinline__ float fcomp(float4 v, int j) {
    return (j == 0) ? v.x : (j == 1) ? v.y : (j == 2) ? v.z : v.w;
}

__global__ void zero_f(float* __restrict__ p, int n) {
    int i = blockIdx.x * blockDim.x + threadIdx.x;
    if (i < n) p[i] = 0.0f;
}

// dst[k][r] = src[r][k], src is [1024][K]; output-coalesced
__global__ void transpose_w(const float* __restrict__ src, float* __restrict__ dst, int K) {
    int idx = blockIdx.x * blockDim.x + threadIdx.x;
    if (idx >= K * 1024) return;
    int r = idx & 1023;
    int k = idx >> 10;
    dst[idx] = src[r * K + k];
}

// Persistent, weight-stationary LSTM.
// 256 blocks x 256 threads, 1 block/CU (4 waves), VGPR budget <=512.
// Block = (dir d, 8-batch tile b0, 32-channel tile c0). Thread = (ks 0..7, rq 0..31).
// Each thread holds its weight slice in VGPRs: L0 = 38 float4, L1 = 96 float4.
// Sync: per-member flag slots (store-only publish, poll 8 slots), one grid
// barrier between layers. h/O0 coherence identical to the round-4 passing kernel.
template<typename OT>
__global__ __launch_bounds__(NT, 1)
void lstm_persist(const float* __restrict__ x,
    const float* __restrict__ wih0f, const float* __restrict__ wih0b,
    const float* __restrict__ whh0f, const float* __restrict__ whh0b,
    const float* __restrict__ bih0f, const float* __restrict__ bhh0f,
    const float* __restrict__ bih0b, const float* __restrict__ bhh0b,
    const float* __restrict__ wih1f, const float* __restrict__ wih1b,
    const float* __restrict__ whh1f, const float* __restrict__ whh1b,
    const float* __restrict__ bih1f, const float* __restrict__ bhh1f,
    const float* __restrict__ bih1b, const float* __restrict__ bhh1b,
    float* __restrict__ h_l0, float* __restrict__ h_l1,
    float* __restrict__ c_l0, float* __restrict__ c_l1,
    OT* __restrict__ O0, const int* __restrict__ lengths, int* __restrict__ flags)
{
    const int bx  = blockIdx.x;
    const int d   = bx >> 7;                 // 0 fwd, 1 bwd
    const int rem = bx & 127;
    const int b0  = (rem >> 3) * 8;
    const int c0  = (rem & 7) * 32;
    const int tid = threadIdx.x;
    const int ks  = tid & 7;                 // 8 k-slices
    const int rq  = tid >> 3;                // 32 row-quads

    const int grp = d * 16 + (rem >> 3);     // sync group (dir, batch-tile): 8 members
    int* grpflags = flags + grp * 8 * 16;
    int* myflag   = grpflags + (rem & 7) * 16;

    const int gate  = rq >> 3;               // rbase = rq*4; gate-major local rows
    const int chl4  = (rq & 7) << 2;
    const int grow0 = gate * 256 + c0 + chl4;    // global gate-row of acc[0] (f4-aligned)

    // gate-math mapping (all 256 threads)
    const int gm_chl = tid & 31;
    const int gm_b   = tid >> 5;
    const int gm_gch = c0 + gm_chl;
    const int my_len = lengths[b0 + gm_b];       // constant per call

    __shared__ float  lds_x0[8 * 52];            // L0 x scalars, row pad 52
    __shared__ float4 lds_x4[8 * 136];           // L1 x f4, slice stride 17
    __shared__ float4 lds_h4[8 * 72];            // h f4, slice stride 9
    __shared__ float  lds_g[128 * 9];            // gates [row][b], pad 9

    // ======================= phase 0: layer 0 =======================
    {
        const float* wih_t = d ? wih0b : wih0f;  // [48][1024]
        const float* whh_t = d ? whh0b : whh0f;  // [256][1024]
        const float* bih   = d ? bih0b : bih0f;
        const float* bhh   = d ? bhh0b : bhh0f;
        float* crow = c_l0 + d * (B * H);
        const float gm_bih[4] = { bih[0*256+gm_gch], bih[1*256+gm_gch], bih[2*256+gm_gch], bih[3*256+gm_gch] };
        const float gm_bhh[4] = { bhh[0*256+gm_gch], bhh[1*256+gm_gch], bhh[2*256+gm_gch], bhh[3*256+gm_gch] };

        // ---- weights -> VGPRs (once) ----
        float4 w0x[6], w0h[32];
        #pragma unroll
        for (int kk = 0; kk < 6; kk++)
            w0x[kk] = *(const float4*)(wih_t + (ks * 6 + kk) * G + grow0);
        #pragma unroll
        for (int i = 0; i < 32; i++)
            w0h[i] = *(const float4*)(whh_t + (ks * 32 + i) * G + grow0);

        #pragma unroll 1
        for (int s = 0; s < T; ++s) {
            const int t = d ? (T - 1 - s) : s;
            const float* hrow_in  = h_l0 + ((size_t)((s & 1) * 2 + d)) * (B * H);
            float*       hrow_out = h_l0 + ((size_t)(((s & 1) ^ 1) * 2 + d)) * (B * H);

            // ---- stage x tile ----
            for (int i = tid; i < 8 * 48; i += NT) {
                int b = i / 48, k = i - b * 48;
                lds_x0[b * 52 + k] = x[((size_t)(b0 + b) * T + t) * DIN + k];
            }
            __syncthreads();

            float acc[4][8];
            #pragma unroll
            for (int i = 0; i < 4; i++)
                #pragma unroll
                for (int b = 0; b < 8; b++) acc[i][b] = 0.0f;

            // ---- x part (before peer-wait: overlaps publish latency) ----
            #pragma unroll
            for (int kk = 0; kk < 6; kk++) {
                float4 w4 = w0x[kk];
                #pragma unroll
                for (int b = 0; b < 8; b++) {
                    float xs = lds_x0[b * 52 + ks * 6 + kk];
                    acc[0][b] = fmaf(w4.x, xs, acc[0][b]);
                    acc[1][b] = fmaf(w4.y, xs, acc[1][b]);
                    acc[2][b] = fmaf(w4.z, xs, acc[2][b]);
                    acc[3][b] = fmaf(w4.w, xs, acc[3][b]);
                }
            }

            // ---- wait: all 8 peers published step s-1 (slot >= s) ----
            if (tid == 0) {
                for (;;) {
                    bool ready = true;
                    #pragma unroll
                    for (int m = 0; m < 8; m++)
                        ready &= (__hip_atomic_load(&grpflags[m * 16], __ATOMIC_RELAXED, __HIP_MEMORY_SCOPE_AGENT) >= s);
                    if (ready) break;
                    __builtin_amdgcn_s_sleep(2);
                }
            }
            __syncthreads();

            // ---- stage h (agent loads -> coherent point) ----
            for (int i = tid; i < 8 * 256; i += NT) {
                int b = i >> 8, k = i & 255;
                float v = __hip_atomic_load(hrow_in + (b0 + b) * H + k,
                                            __ATOMIC_RELAXED, __HIP_MEMORY_SCOPE_AGENT);
                ((float*)lds_h4)[(b * 72 + (k >> 5) * 9 + ((k >> 2) & 7)) * 4 + (k & 3)] = v;
            }
            __syncthreads();

            // ---- h part ----
            #pragma unroll
            for (int kk2 = 0; kk2 < 8; kk2++) {
                #pragma unroll
                for (int b = 0; b < 8; b++) {
                    float4 hv = lds_h4[b * 72 + ks * 9 + kk2];
                    #pragma unroll
                    for (int j = 0; j < 4; j++) {
                        float4 w4 = w0h[kk2 * 4 + j];
                        float hs = fcomp(hv, j);
                        acc[0][b] = fmaf(w4.x, hs, acc[0][b]);
                        acc[1][b] = fmaf(w4.y, hs, acc[1][b]);
                        acc[2][b] = fmaf(w4.z, hs, acc[2][b]);
                        acc[3][b] = fmaf(w4.w, hs, acc[3][b]);
                    }
                }
            }

            // ---- reduce over 8 k-slices (lane bits 0..2) ----
            #pragma unroll
            for (int i = 0; i < 4; i++)
                #pragma unroll
                for (int b = 0; b < 8; b++) {
                    float v = acc[i][b];
                    v += __shfl_xor(v, 1, 64);
                    v += __shfl_xor(v, 2, 64);
                    v += __shfl_xor(v, 4, 64);
                    acc[i][b] = v;
                }
            if (ks == 0) {
                #pragma unroll
                for (int i = 0; i < 4; i++)
                    #pragma unroll
                    for (int b = 0; b < 8; b++)
                        lds_g[(rq * 4 + i) * 9 + b] = acc[i][b];
            }
            __syncthreads();

            // ---- gate math (all 256 threads) ----
            {
                float gi = lds_g[(0 * 32 + gm_chl) * 9 + gm_b] + gm_bih[0] + gm_bhh[0];
                float gf = lds_g[(1 * 32 + gm_chl) * 9 + gm_b] + gm_bih[1] + gm_bhh[1];
                float gg = lds_g[(2 * 32 + gm_chl) * 9 + gm_b] + gm_bih[2] + gm_bhh[2];
                float go = lds_g[(3 * 32 + gm_chl) * 9 + gm_b] + gm_bih[3] + gm_bhh[3];
                float iv = sigmoidf_(gi);
                float fv = sigmoidf_(gf);
                float gv = tanhf_(gg);
                float ov = sigmoidf_(go);
                const int sidx = (b0 + gm_b) * H + gm_gch;
                float c_old = crow[sidx];
                float h_old = ((float*)lds_h4)[(gm_b * 72 + (gm_gch >> 5) * 9 + ((gm_gch >> 2) & 7)) * 4 + (gm_gch & 3)];
                float c_new = fv * c_old + iv * gv;
                float h_new = ov * tanhf_(c_new);
                bool valid = t < my_len;
                if (valid) crow[sidx] = c_new;
                __hip_atomic_store(hrow_out + sidx, valid ? h_new : h_old,
                                   __ATOMIC_RELAXED, __HIP_MEMORY_SCOPE_AGENT);
                float hv_o = valid ? h_new : 0.0f;
                size_t oidx = ((size_t)(b0 + gm_b) * T + t) * 512 + d * 256 + gm_gch;
                if constexpr (sizeof(OT) == 4)
                    __hip_atomic_store(O0 + oidx, hv_o, __ATOMIC_RELAXED, __HIP_MEMORY_SCOPE_AGENT);
                else
                    __hip_atomic_store(O0 + oidx, f2bf(hv_o), __ATOMIC_RELAXED, __HIP_MEMORY_SCOPE_AGENT);
            }
            __syncthreads();   // drain h/O0 stores (vmcnt) before publish
            if (tid == 0)
                __hip_atomic_store(myflag, s + 1, __ATOMIC_RELAXED, __HIP_MEMORY_SCOPE_AGENT);
        }
    }

    // ======================= grid-wide phase barrier =======================
    __syncthreads();
    if (tid == 0) {
        __threadfence();
        __hip_atomic_fetch_add(&flags[32 * 8 * 16], 1, __ATOMIC_ACQ_REL, __HIP_MEMORY_SCOPE_AGENT);
        while (__hip_atomic_load(&flags[32 * 8 * 16], __ATOMIC_ACQUIRE, __HIP_MEMORY_SCOPE_AGENT) < 256)
            __builtin_amdgcn_s_sleep(2);
        __threadfence();
    }
    __syncthreads();

    // ======================= phase 1: layer 1 =======================
    {
        const float* wih_t = d ? wih1b : wih1f;  // [512][1024]
        const float* whh_t = d ? whh1b : whh1f;  // [256][1024]
        const float* bih   = d ? bih1b : bih1f;
        const float* bhh   = d ? bhh1b : bhh1f;
        float* crow = c_l1 + d * (B * H);
        const float gm_bih[4] = { bih[0*256+gm_gch], bih[1*256+gm_gch], bih[2*256+gm_gch], bih[3*256+gm_gch] };
        const float gm_bhh[4] = { bhh[0*256+gm_gch], bhh[1*256+gm_gch], bhh[2*256+gm_gch], bhh[3*256+gm_gch] };

        // ---- weights -> VGPRs (once): 96 float4 / thread ----
        float4 w1x[64], w1h[32];
        #pragma unroll
        for (int i = 0; i < 64; i++)
            w1x[i] = *(const float4*)(wih_t + (ks * 64 + i) * G + grow0);
        #pragma unroll
        for (int i = 0; i < 32; i++)
            w1h[i] = *(const float4*)(whh_t + (ks * 32 + i) * G + grow0);

        #pragma unroll 1
        for (int s = 0; s < T; ++s) {
            const int t = d ? (T - 1 - s) : s;
            const float* hrow_in  = h_l1 + ((size_t)((s & 1) * 2 + d)) * (B * H);
            float*       hrow_out = h_l1 + ((size_t)(((s & 1) ^ 1) * 2 + d)) * (B * H);

            // ---- stage x tile from O0 (plain loads; grid barrier made it visible) ----
            for (int i = tid; i < 8 * 128; i += NT) {
                int b = i >> 7, kq = i & 127;
                float4 v;
                if constexpr (sizeof(OT) == 4) {
                    v = *(const float4*)((const float*)O0 + ((size_t)(b0 + b) * T + t) * 512 + kq * 4);
                } else {
                    ushort4 uv = *(const ushort4*)((const unsigned short*)O0 + ((size_t)(b0 + b) * T + t) * 512 + kq * 4);
                    v = make_float4(bf2f(uv.x), bf2f(uv.y), bf2f(uv.z), bf2f(uv.w));
                }
                lds_x4[b * 136 + (kq >> 4) * 17 + (kq & 15)] = v;
            }
            __syncthreads();

            float acc[4][8];
            #pragma unroll
            for (int i = 0; i < 4; i++)
                #pragma unroll
                for (int b = 0; b < 8; b++) acc[i][b] = 0.0f;

            // ---- x part: 2048 FMAs/thread, before peer-wait ----
            #pragma unroll
            for (int kk2 = 0; kk2 < 16; kk2++) {
                #pragma unroll
                for (int b = 0; b < 8; b++) {
                    float4 xv = lds_x4[b * 136 + ks * 17 + kk2];
                    #pragma unroll
                    for (int j = 0; j < 4; j++) {
                        float4 w4 = w1x[kk2 * 4 + j];
                        float xs = fcomp(xv, j);
                        acc[0][b] = fmaf(w4.x, xs, acc[0][b]);
                        acc[1][b] = fmaf(w4.y, xs, acc[1][b]);
                        acc[2][b] = fmaf(w4.z, xs, acc[2][b]);
                        acc[3][b] = fmaf(w4.w, xs, acc[3][b]);
                    }
                }
            }

            // ---- wait: all 8 peers >= T + s ----
            if (tid == 0) {
                const int target = T + s;
                for (;;) {
                    bool ready = true;
                    #pragma unroll
                    for (int m = 0; m < 8; m++)
                        ready &= (__hip_atomic_load(&grpflags[m * 16], __ATOMIC_RELAXED, __HIP_MEMORY_SCOPE_AGENT) >= target);
                    if (ready) break;
                    __builtin_amdgcn_s_sleep(2);
                }
            }
            __syncthreads();

            // ---- stage h ----
            for (int i = tid; i < 8 * 256; i += NT) {
                int b = i >> 8, k = i & 255;
                float v = __hip_atomic_load(hrow_in + (b0 + b) * H + k,
                                            __ATOMIC_RELAXED, __HIP_MEMORY_SCOPE_AGENT);
                ((float*)lds_h4)[(b * 72 + (k >> 5) * 9 + ((k >> 2) & 7)) * 4 + (k & 3)] = v;
            }
            __syncthreads();

            // ---- h part ----
            #pragma unroll
            for (int kk2 = 0; kk2 < 8; kk2++) {
                #pragma unroll
                for (int b = 0; b < 8; b++) {
                    float4 hv = lds_h4[b * 72 + ks * 9 + kk2];
                    #pragma unroll
                    for (int j = 0; j < 4; j++) {
                        float4 w4 = w1h[kk2 * 4 + j];
                        float hs = fcomp(hv, j);
                        acc[0][b] = fmaf(w4.x, hs, acc[0][b]);
                        acc[1][b] = fmaf(w4.y, hs, acc[1][b]);
                        acc[2][b] = fmaf(w4.z, hs, acc[2][b]);
                        acc[3][b] = fmaf(w4.w, hs, acc[3][b]);
                    }
                }
            }

            // ---- reduce over 8 k-slices ----
            #pragma unroll
            for (int i = 0; i < 4; i++)
                #pragma unroll
                for (int b = 0; b < 8; b++) {
                    float v = acc[i][b];
                    v += __shfl_xor(v, 1, 64);
                    v += __shfl_xor(v, 2, 64);
                    v += __shfl_xor(v, 4, 64);
                    acc[i][b] = v;
                }
            if (ks == 0) {
                #pragma unroll
                for (int i = 0; i < 4; i++)
                    #pragma unroll
                    for (int b = 0; b < 8; b++)
                        lds_g[(rq * 4 + i) * 9 + b] = acc[i][b];
            }
            __syncthreads();

            // ---- gate math ----
            {
                float gi = lds_g[(0 * 32 + gm_chl) * 9 + gm_b] + gm_bih[0] + gm_bhh[0];
                float gf = lds_g[(1 * 32 + gm_chl) * 9 + gm_b] + gm_bih[1] + gm_bhh[1];
                float gg = lds_g[(2 * 32 + gm_chl) * 9 + gm_b] + gm_bih[2] + gm_bhh[2];
                float go = lds_g[(3 * 32 + gm_chl) * 9 + gm_b] + gm_bih[3] + gm_bhh[3];
                float iv = sigmoidf_(gi);
                float fv = sigmoidf_(gf);
                float gv = tanhf_(gg);
                float ov = sigmoidf_(go);
                const int sidx = (b0 + gm_b) * H + gm_gch;
                float c_old = crow[sidx];
                float h_old = ((float*)lds_h4)[(gm_b * 72 + (gm_gch >> 5) * 9 + ((gm_gch >> 2) & 7)) * 4 + (gm_gch & 3)];
                float c_new = fv * c_old + iv * gv;
                float h_new = ov * tanhf_(c_new);
                bool valid = t < my_len;
                if (valid) crow[sidx] = c_new;
                __hip_atomic_store(hrow_out + sidx, valid ? h_new : h_old,
                                   __ATOMIC_RELAXED, __HIP_MEMORY_SCOPE_AGENT);
            }
            __syncthreads();
            if (tid == 0)
                __hip_atomic_store(myflag, T + s + 1, __ATOMIC_RELAXED, __HIP_MEMORY_SCOPE_AGENT);
        }
    }
}

__global__ __launch_bounds__(256)
void fc_head(const float* __restrict__ h1,   // [2][B][H] final layer-1 h (parity 0)
             const float* __restrict__ fc1w, const float* __restrict__ fc1b,
             const float* __restrict__ fc2w, const float* __restrict__ fc2b,
             float* __restrict__ out)
{
    int b = blockIdx.x;
    int tid = threadIdx.x;
    __shared__ float hid[512];
    __shared__ float red[4];
    hid[tid]       = h1[b * H + tid];
    hid[256 + tid] = h1[(size_t)B * H + b * H + tid];
    __syncthreads();
    float a = fc1b[tid];
    const float4* w4 = (const float4*)(fc1w + tid * 512);
    const float4* h4 = (const float4*)hid;
    #pragma unroll 4
    for (int k = 0; k < 128; k++) {
        float4 w = w4[k], h = h4[k];
        a = fmaf(w.x, h.x, a); a = fmaf(w.y, h.y, a);
        a = fmaf(w.z, h.z, a); a = fmaf(w.w, h.w, a);
    }
    float r = fmaxf(a, 0.0f);
    float v = r * fc2w[tid];
    #pragma unroll
    for (int off = 32; off > 0; off >>= 1) v += __shfl_down(v, off, 64);
    if ((tid & 63) == 0) red[tid >> 6] = v;
    __syncthreads();
    if (tid == 0) out[b] = red[0] + red[1] + red[2] + red[3] + fc2b[0];
}

} // namespace

extern "C" void kernel_launch(void* const* d_in, const int* in_sizes, int n_in,
                              void* d_out, int out_size, void* d_ws, size_t ws_size,
                              hipStream_t stream)
{
    const float* x        = (const float*)d_in[0];
    const int*   lengths  = (const int*)d_in[1];
    const float* w_ih_l0f = (const float*)d_in[2];
    const float* w_hh_l0f = (const float*)d_in[3];
    const float* b_ih_l0f = (const float*)d_in[4];
    const float* b_hh_l0f = (const float*)d_in[5];
    const float* w_ih_l0b = (const float*)d_in[6];
    const float* w_hh_l0b = (const float*)d_in[7];
    const float* b_ih_l0b = (const float*)d_in[8];
    const float* b_hh_l0b = (const float*)d_in[9];
    const float* w_ih_l1f = (const float*)d_in[10];
    const float* w_hh_l1f = (const float*)d_in[11];
    const float* b_ih_l1f = (const float*)d_in[12];
    const float* b_hh_l1f = (const float*)d_in[13];
    const float* w_ih_l1b = (const float*)d_in[14];
    const float* w_hh_l1b = (const float*)d_in[15];
    const float* b_ih_l1b = (const float*)d_in[16];
    const float* b_hh_l1b = (const float*)d_in[17];
    const float* fc1w     = (const float*)d_in[18];
    const float* fc1b     = (const float*)d_in[19];
    const float* fc2w     = (const float*)d_in[20];
    const float* fc2b     = (const float*)d_in[21];

    float* ws = (float*)d_ws;

    // ---- workspace layout: [weights | state | flags | O0] ----
    float* whh_t_l0f = ws;
    float* whh_t_l0b = whh_t_l0f + 256 * 1024;
    float* whh_t_l1f = whh_t_l0b + 256 * 1024;
    float* whh_t_l1b = whh_t_l1f + 256 * 1024;
    float* wih_t_l0f = whh_t_l1b + 256 * 1024;  // [48][1024]
    float* wih_t_l0b = wih_t_l0f + 48 * 1024;
    float* wih_t_l1f = wih_t_l0b + 48 * 1024;   // [512][1024]
    float* wih_t_l1b = wih_t_l1f + 512 * 1024;

    float* state = ws + WT_FLOATS;
    float* h_l0 = state;                        // [2 parity][2 dir][B][H]
    float* h_l1 = h_l0 + 4 * BH;
    float* c_l0 = h_l1 + 4 * BH;                // [2 dir][B][H]
    float* c_l1 = c_l0 + 2 * BH;
    int*   flags = (int*)(state + STATE_FLOATS);
    void*  O0   = (void*)(state + STATE_FLOATS + FLAG_INTS);

    // ws_size is invariant across calls -> deterministic branch.
    const size_t base_bytes = (WT_FLOATS + STATE_FLOATS + FLAG_INTS) * sizeof(float);
    const bool o0_f32 = ws_size >= base_bytes + O0_ELEMS * sizeof(float);

    // zero h/c state AND sync flags (ws is poisoned 0xAA before every call)
    zero_f<<<(int)((STATE_FLOATS + FLAG_INTS + 255) / 256), 256, 0, stream>>>(
        state, (int)(STATE_FLOATS + FLAG_INTS));

    // weight transposes (per call; cheap, graph-captured)
    transpose_w<<<256 * 1024 / 256, 256, 0, stream>>>(w_hh_l0f, whh_t_l0f, 256);
    transpose_w<<<256 * 1024 / 256, 256, 0, stream>>>(w_hh_l0b, whh_t_l0b, 256);
    transpose_w<<<256 * 1024 / 256, 256, 0, stream>>>(w_hh_l1f, whh_t_l1f, 256);
    transpose_w<<<256 * 1024 / 256, 256, 0, stream>>>(w_hh_l1b, whh_t_l1b, 256);
    transpose_w<<<48 * 1024 / 256, 256, 0, stream>>>(w_ih_l0f, wih_t_l0f, 48);
    transpose_w<<<48 * 1024 / 256, 256, 0, stream>>>(w_ih_l0b, wih_t_l0b, 48);
    transpose_w<<<512 * 1024 / 256, 256, 0, stream>>>(w_ih_l1f, wih_t_l1f, 512);
    transpose_w<<<512 * 1024 / 256, 256, 0, stream>>>(w_ih_l1b, wih_t_l1b, 512);

    if (o0_f32) {
        lstm_persist<float><<<256, NT, 0, stream>>>(
            x,
            wih_t_l0f, wih_t_l0b, whh_t_l0f, whh_t_l0b,
            b_ih_l0f, b_hh_l0f, b_ih_l0b, b_hh_l0b,
            wih_t_l1f, wih_t_l1b, whh_t_l1f, whh_t_l1b,
            b_ih_l1f, b_hh_l1f, b_ih_l1b, b_hh_l1b,
            h_l0, h_l1, c_l0, c_l1,
            (float*)O0, lengths, flags);
    } else {
        lstm_persist<unsigned short><<<256, NT, 0, stream>>>(
            x,
            wih_t_l0f, wih_t_l0b, whh_t_l0f, whh_t_l0b,
            b_ih_l0f, b_hh_l0f, b_ih_l0b, b_hh_l0b,
            wih_t_l1f, wih_t_l1b, whh_t_l1f, whh_t_l1b,
            b_ih_l1f, b_hh_l1f, b_ih_l1b, b_hh_l1b,
            h_l0, h_l1, c_l0, c_l1,
            (unsigned short*)O0, lengths, flags);
    }
    // FC head: T even -> final h lives at parity 0
    fc_head<<<B, 256, 0, stream>>>(h_l1, fc1w, fc1b, fc2w, fc2b, (float*)d_out);
}